// Round 1
// baseline (14657.726 us; speedup 1.0000x reference)
//
#include <hip/hip_runtime.h>
#include <hip/hip_bf16.h>

// Problem: 2-layer LSTM, B=64, F=128, T=1024, H=512. Output = h_T of layer 1 (64x512 fp32).
// Strategy: single persistent kernel, 128 WGs; each WG owns 4 h-columns (16 gate rows)
// per layer with weight rows resident in LDS (bf16). One custom grid barrier per
// timestep; layers pipelined one step apart. h state published in bf16 (double-buffered
// global); c state in registers (fp32). MFMA 16x16x32 bf16, fp32 accumulate.

#define B_ 64
#define F_ 128
#define T_ 1024
#define H_ 512
#define NWG 128

typedef __bf16 bf16x8 __attribute__((ext_vector_type(8)));
typedef float f32x4 __attribute__((ext_vector_type(4)));

#define SH 520   // padded LDS row stride for K=512 (breaks bank aliasing)
#define SF 136   // padded LDS row stride for K=128

__device__ __forceinline__ float sigm(float x) { return 1.0f / (1.0f + __expf(-x)); }
__device__ __forceinline__ float tanh_fast(float x) { return 1.0f - 2.0f / (__expf(2.0f * x) + 1.0f); }

// Sense-reversing grid barrier, agent scope. Safe: cnt reset happens-before gen bump;
// arrivals for next generation only occur after observing the bump.
__device__ __forceinline__ void grid_barrier(unsigned* cnt, unsigned* gen) {
  __syncthreads();
  if (threadIdx.x == 0) {
    __threadfence();  // release prior publishes (agent scope)
    unsigned g = __hip_atomic_load(gen, __ATOMIC_RELAXED, __HIP_MEMORY_SCOPE_AGENT);
    unsigned a = __hip_atomic_fetch_add(cnt, 1u, __ATOMIC_ACQ_REL, __HIP_MEMORY_SCOPE_AGENT);
    if (a == NWG - 1) {
      __hip_atomic_store(cnt, 0u, __ATOMIC_RELAXED, __HIP_MEMORY_SCOPE_AGENT);
      __hip_atomic_fetch_add(gen, 1u, __ATOMIC_ACQ_REL, __HIP_MEMORY_SCOPE_AGENT);
    } else {
      while (__hip_atomic_load(gen, __ATOMIC_RELAXED, __HIP_MEMORY_SCOPE_AGENT) == g)
        __builtin_amdgcn_s_sleep(2);
    }
    __threadfence();  // acquire: invalidate stale cached h before this iteration's reads
  }
  __syncthreads();
}

// x (B,F,T) fp32 -> xT (T,B,F) bf16, tiled via LDS for coalescing on both sides.
__global__ __launch_bounds__(256) void transpose_x_kernel(const float* __restrict__ x,
                                                          __bf16* __restrict__ xT) {
  __shared__ float tile[F_][65];
  const int bb = blockIdx.x >> 4;   // batch 0..63
  const int tt = blockIdx.x & 15;   // t-tile (64 steps each)
  const int tid = threadIdx.x;
  const int tl = tid & 63;
  const int f0 = tid >> 6;          // 0..3
  for (int fo = 0; fo < F_; fo += 4) {
    int f = fo + f0;
    tile[f][tl] = x[((size_t)bb * F_ + f) * T_ + tt * 64 + tl];
  }
  __syncthreads();
  const int fw = tid & 127;
  const int tg = tid >> 7;          // 0..1
  for (int to = 0; to < 64; to += 2) {
    int t = to + tg;
    xT[((size_t)(tt * 64 + t) * B_ + bb) * F_ + fw] = (__bf16)tile[fw][t];
  }
}

__global__ __launch_bounds__(256, 1) void lstm_persistent(
    const __bf16* __restrict__ xT,
    const float* __restrict__ Wih0, const float* __restrict__ Whh0,
    const float* __restrict__ bih0, const float* __restrict__ bhh0,
    const float* __restrict__ Wih1, const float* __restrict__ Whh1,
    const float* __restrict__ bih1, const float* __restrict__ bhh1,
    __bf16* h0_pub, __bf16* h1_pub,   // each: [2][B][H] bf16, double-buffered
    unsigned* bar_cnt, unsigned* bar_gen,
    float* __restrict__ out) {
  // LDS-resident weight slices (bf16), 16 gate rows per layer-matrix per WG
  __shared__ __bf16 sW0i[16 * SF];   //  4,352 B
  __shared__ __bf16 sW0h[16 * SH];   // 16,640 B
  __shared__ __bf16 sW1i[16 * SH];   // 16,640 B
  __shared__ __bf16 sW1h[16 * SH];   // 16,640 B
  __shared__ float sG0[4][256];      //  4,096 B  gate staging (activated)
  __shared__ float sG1[4][256];      //  4,096 B   -> total 62,464 B < 64 KB

  const int wg   = blockIdx.x;
  const int tid  = threadIdx.x;
  const int wv   = tid >> 6;         // wave 0..3 -> batch tile
  const int lane = tid & 63;
  const int p    = lane >> 4;        // quad: MFMA k-group / writer gate-type / reader j
  const int l15  = lane & 15;        // MFMA m (A row) and n (B col / batch)
  const int b    = wv * 16 + l15;    // this lane's batch (B operand / elementwise)
  const int ks   = p * 8;            // k offset inside a 32-chunk

  // Load weight rows -> LDS bf16. gate row for local m: (m>>2)*H + wg*4 + (m&3)
  for (int m = 0; m < 16; ++m) {
    const int grow = (m >> 2) * H_ + wg * 4 + (m & 3);
    for (int k = tid; k < F_; k += 256) sW0i[m * SF + k] = (__bf16)Wih0[grow * F_ + k];
    for (int k = tid; k < H_; k += 256) sW0h[m * SH + k] = (__bf16)Whh0[grow * H_ + k];
    for (int k = tid; k < H_; k += 256) sW1i[m * SH + k] = (__bf16)Wih1[grow * H_ + k];
    for (int k = tid; k < H_; k += 256) sW1h[m * SH + k] = (__bf16)Whh1[grow * H_ + k];
  }
  // Writer-lane biases: gate-type q=p, local col r
  float b0q[4], b1q[4];
  for (int r = 0; r < 4; ++r) {
    const int grow = p * H_ + wg * 4 + r;
    b0q[r] = bih0[grow] + bhh0[grow];
    b1q[r] = bih1[grow] + bhh1[grow];
  }
  __syncthreads();

  float c0 = 0.f, c1 = 0.f;

  for (int it = 0; it <= T_; ++it) {
    // double buffer: read generation (it-1), write generation it
    const __bf16* h0r = h0_pub + ((it + 1) & 1) * (B_ * H_);
    const __bf16* h1r = h1_pub + ((it + 1) & 1) * (B_ * H_);
    __bf16* h0w = h0_pub + (it & 1) * (B_ * H_);
    __bf16* h1w = h1_pub + (it & 1) * (B_ * H_);

    f32x4 acc0  = {0.f, 0.f, 0.f, 0.f};   // Whh0 * h0
    f32x4 acc0b = {0.f, 0.f, 0.f, 0.f};   // Wih0 * x_t
    f32x4 acc1a = {0.f, 0.f, 0.f, 0.f};   // Wih1 * h0 (=out0[t-1])
    f32x4 acc1b = {0.f, 0.f, 0.f, 0.f};   // Whh1 * h1

#pragma unroll
    for (int kc = 0; kc < 16; ++kc) {
      const int k0 = kc * 32 + ks;
      bf16x8 hb0 = *(const bf16x8*)&h0r[b * H_ + k0];
      bf16x8 hb1 = *(const bf16x8*)&h1r[b * H_ + k0];
      bf16x8 a0  = *(const bf16x8*)&sW0h[l15 * SH + k0];
      bf16x8 a1i = *(const bf16x8*)&sW1i[l15 * SH + k0];
      bf16x8 a1h = *(const bf16x8*)&sW1h[l15 * SH + k0];
      acc0  = __builtin_amdgcn_mfma_f32_16x16x32_bf16(a0,  hb0, acc0,  0, 0, 0);
      acc1a = __builtin_amdgcn_mfma_f32_16x16x32_bf16(a1i, hb0, acc1a, 0, 0, 0);
      acc1b = __builtin_amdgcn_mfma_f32_16x16x32_bf16(a1h, hb1, acc1b, 0, 0, 0);
    }
    {
      const int t = (it < T_) ? it : (T_ - 1);  // clamped; result unused at it==T
      const __bf16* xrow = xT + ((size_t)t * B_ + b) * F_;
#pragma unroll
      for (int kc = 0; kc < 4; ++kc) {
        const int k0 = kc * 32 + ks;
        bf16x8 xb = *(const bf16x8*)&xrow[k0];
        bf16x8 a  = *(const bf16x8*)&sW0i[l15 * SF + k0];
        acc0b = __builtin_amdgcn_mfma_f32_16x16x32_bf16(a, xb, acc0b, 0, 0, 0);
      }
    }

    // Writer phase: lane holds C rows m=4p+r (gate q=p, local col r), batch col l15.
    // Apply bias + activation, stage to LDS for the (q -> lane) reshuffle.
#pragma unroll
    for (int r = 0; r < 4; ++r) {
      float v0 = acc0[r] + acc0b[r] + b0q[r];
      float v1 = acc1a[r] + acc1b[r] + b1q[r];
      float a0v = (p == 2) ? tanh_fast(v0) : sigm(v0);
      float a1v = (p == 2) ? tanh_fast(v1) : sigm(v1);
      sG0[wv][p * 64 + r * 16 + l15] = a0v;
      sG1[wv][p * 64 + r * 16 + l15] = a1v;
    }
    __syncthreads();

    // Reader phase: lane <-> (j=p local col, batch l15)
    if (it < T_) {
      float gi = sG0[wv][0 * 64 + p * 16 + l15];
      float gf = sG0[wv][1 * 64 + p * 16 + l15];
      float gg = sG0[wv][2 * 64 + p * 16 + l15];
      float go = sG0[wv][3 * 64 + p * 16 + l15];
      c0 = gf * c0 + gi * gg;
      float h = go * tanh_fast(c0);
      h0w[b * H_ + wg * 4 + p] = (__bf16)h;
    }
    if (it > 0) {
      float gi = sG1[wv][0 * 64 + p * 16 + l15];
      float gf = sG1[wv][1 * 64 + p * 16 + l15];
      float gg = sG1[wv][2 * 64 + p * 16 + l15];
      float go = sG1[wv][3 * 64 + p * 16 + l15];
      c1 = gf * c1 + gi * gg;
      float h = go * tanh_fast(c1);
      if (it < T_) h1w[b * H_ + wg * 4 + p] = (__bf16)h;
      else         out[b * H_ + wg * 4 + p] = h;   // final: fp32 output
    }

    if (it != T_) grid_barrier(bar_cnt, bar_gen);
  }
}

// Workspace layout:
//   [0]        bar_cnt (4B);  [256] bar_gen (4B)
//   [4096]                h0_pub: 2*64*512*2 = 131072 B
//   [4096+131072]         h1_pub: 131072 B
//   [0x60000 = 393216]    xT: 1024*64*128*2 = 16 MiB
// total required ~17.2 MB. Zeroed region: [0, 266240).
extern "C" void kernel_launch(void* const* d_in, const int* in_sizes, int n_in,
                              void* d_out, int out_size, void* d_ws, size_t ws_size,
                              hipStream_t stream) {
  const float* x    = (const float*)d_in[0];
  const float* Wih0 = (const float*)d_in[1];
  const float* Whh0 = (const float*)d_in[2];
  const float* bih0 = (const float*)d_in[3];
  const float* bhh0 = (const float*)d_in[4];
  const float* Wih1 = (const float*)d_in[5];
  const float* Whh1 = (const float*)d_in[6];
  const float* bih1 = (const float*)d_in[7];
  const float* bhh1 = (const float*)d_in[8];
  float* out = (float*)d_out;

  char* ws = (char*)d_ws;
  unsigned* bar_cnt = (unsigned*)ws;
  unsigned* bar_gen = (unsigned*)(ws + 256);
  __bf16* h0p = (__bf16*)(ws + 4096);
  __bf16* h1p = (__bf16*)(ws + 4096 + 2 * B_ * H_ * 2);
  __bf16* xT  = (__bf16*)(ws + 0x60000);

  // zero barrier state + both generations of h0/h1 (ws is poisoned 0xAA each launch)
  hipMemsetAsync(ws, 0, 4096 + 4 * B_ * H_ * 2, stream);

  transpose_x_kernel<<<dim3(B_ * 16), dim3(256), 0, stream>>>(x, xT);

  lstm_persistent<<<dim3(NWG), dim3(256), 0, stream>>>(
      xT, Wih0, Whh0, bih0, bhh0, Wih1, Whh1, bih1, bhh1,
      h0p, h1p, bar_cnt, bar_gen, out);
}

// Round 2
// 8021.930 us; speedup vs baseline: 1.8272x; 1.8272x over previous
//
#include <hip/hip_runtime.h>
#include <hip/hip_bf16.h>

// 2-layer LSTM, B=64, F=128, T=1024, H=512. Output = h_T of layer 1 (64x512 fp32).
// Persistent kernel, 128 WGs, weights LDS-resident (bf16), MFMA 16x16x32.
// R2 changes vs R1 (14.6ms, 14.3us/iter, sync-bound):
//  - barrier: per-WG flag lines + parallel-lane polling (no atomic RMW contention)
//  - release: h published via relaxed agent atomic dword stores (sc0 sc1 write-through)
//    + syncthreads vmcnt drain -> NO buffer_wbl2 anywhere
//  - acquire: single wave0 fence(acquire, agent) per WG per iter (buffer_inv only)
//  - h buffers rotate over 4 generations (fixes latent 2-deep WAR race in R1)

#define B_ 64
#define F_ 128
#define T_ 1024
#define H_ 512
#define NWG 128

typedef __bf16 bf16x8 __attribute__((ext_vector_type(8)));
typedef float f32x4 __attribute__((ext_vector_type(4)));

#define SH 520   // padded LDS row stride for K=512
#define SF 136   // padded LDS row stride for K=128

__device__ __forceinline__ float sigm(float x) { return 1.0f / (1.0f + __expf(-x)); }
__device__ __forceinline__ float tanh_fast(float x) { return 1.0f - 2.0f / (__expf(2.0f * x) + 1.0f); }

// x (B,F,T) fp32 -> xT (T,B,F) bf16
__global__ __launch_bounds__(256) void transpose_x_kernel(const float* __restrict__ x,
                                                          __bf16* __restrict__ xT) {
  __shared__ float tile[F_][65];
  const int bb = blockIdx.x >> 4;
  const int tt = blockIdx.x & 15;
  const int tid = threadIdx.x;
  const int tl = tid & 63;
  const int f0 = tid >> 6;
  for (int fo = 0; fo < F_; fo += 4) {
    int f = fo + f0;
    tile[f][tl] = x[((size_t)bb * F_ + f) * T_ + tt * 64 + tl];
  }
  __syncthreads();
  const int fw = tid & 127;
  const int tg = tid >> 7;
  for (int to = 0; to < 64; to += 2) {
    int t = to + tg;
    xT[((size_t)(tt * 64 + t) * B_ + bb) * F_ + fw] = (__bf16)tile[fw][t];
  }
}

__global__ __launch_bounds__(256, 1) void lstm_persistent(
    const __bf16* __restrict__ xT,
    const float* __restrict__ Wih0, const float* __restrict__ Whh0,
    const float* __restrict__ bih0, const float* __restrict__ bhh0,
    const float* __restrict__ Wih1, const float* __restrict__ Whh1,
    const float* __restrict__ bih1, const float* __restrict__ bhh1,
    __bf16* h0_pub, __bf16* h1_pub,   // each: [4][B][H] bf16, 4-gen rotation
    unsigned* flags,                   // [NWG] padded to 64B lines
    float* __restrict__ out) {
  __shared__ __bf16 sW0i[16 * SF];
  __shared__ __bf16 sW0h[16 * SH];
  __shared__ __bf16 sW1i[16 * SH];
  __shared__ __bf16 sW1h[16 * SH];
  __shared__ float sG0[4][256];
  __shared__ float sG1[4][256];
  __shared__ unsigned short sH0[64][4];  // h bits staging for packed publish
  __shared__ unsigned short sH1[64][4];

  const int wg   = blockIdx.x;
  const int tid  = threadIdx.x;
  const int wv   = tid >> 6;
  const int lane = tid & 63;
  const int p    = lane >> 4;
  const int l15  = lane & 15;
  const int b    = wv * 16 + l15;
  const int ks   = p * 8;

  for (int m = 0; m < 16; ++m) {
    const int grow = (m >> 2) * H_ + wg * 4 + (m & 3);
    for (int k = tid; k < F_; k += 256) sW0i[m * SF + k] = (__bf16)Wih0[grow * F_ + k];
    for (int k = tid; k < H_; k += 256) sW0h[m * SH + k] = (__bf16)Whh0[grow * H_ + k];
    for (int k = tid; k < H_; k += 256) sW1i[m * SH + k] = (__bf16)Wih1[grow * H_ + k];
    for (int k = tid; k < H_; k += 256) sW1h[m * SH + k] = (__bf16)Whh1[grow * H_ + k];
  }
  float b0q[4], b1q[4];
  for (int r = 0; r < 4; ++r) {
    const int grow = p * H_ + wg * 4 + r;
    b0q[r] = bih0[grow] + bhh0[grow];
    b1q[r] = bih1[grow] + bhh1[grow];
  }
  __syncthreads();

  float c0 = 0.f, c1 = 0.f;

  for (int it = 0; it <= T_; ++it) {
    const int gen_r = (it + 3) & 3;  // generation it-1
    const int gen_w = it & 3;        // generation it
    const __bf16* h0r = h0_pub + gen_r * (B_ * H_);
    const __bf16* h1r = h1_pub + gen_r * (B_ * H_);
    unsigned* h0w = (unsigned*)(h0_pub + gen_w * (B_ * H_));
    unsigned* h1w = (unsigned*)(h1_pub + gen_w * (B_ * H_));

    f32x4 acc0  = {0.f, 0.f, 0.f, 0.f};
    f32x4 acc0b = {0.f, 0.f, 0.f, 0.f};
    f32x4 acc1a = {0.f, 0.f, 0.f, 0.f};
    f32x4 acc1b = {0.f, 0.f, 0.f, 0.f};

#pragma unroll
    for (int kc = 0; kc < 16; ++kc) {
      const int k0 = kc * 32 + ks;
      bf16x8 hb0 = *(const bf16x8*)&h0r[b * H_ + k0];
      bf16x8 hb1 = *(const bf16x8*)&h1r[b * H_ + k0];
      bf16x8 a0  = *(const bf16x8*)&sW0h[l15 * SH + k0];
      bf16x8 a1i = *(const bf16x8*)&sW1i[l15 * SH + k0];
      bf16x8 a1h = *(const bf16x8*)&sW1h[l15 * SH + k0];
      acc0  = __builtin_amdgcn_mfma_f32_16x16x32_bf16(a0,  hb0, acc0,  0, 0, 0);
      acc1a = __builtin_amdgcn_mfma_f32_16x16x32_bf16(a1i, hb0, acc1a, 0, 0, 0);
      acc1b = __builtin_amdgcn_mfma_f32_16x16x32_bf16(a1h, hb1, acc1b, 0, 0, 0);
    }
    {
      const int t = (it < T_) ? it : (T_ - 1);
      const __bf16* xrow = xT + ((size_t)t * B_ + b) * F_;
#pragma unroll
      for (int kc = 0; kc < 4; ++kc) {
        const int k0 = kc * 32 + ks;
        bf16x8 xb = *(const bf16x8*)&xrow[k0];
        bf16x8 a  = *(const bf16x8*)&sW0i[l15 * SF + k0];
        acc0b = __builtin_amdgcn_mfma_f32_16x16x32_bf16(a, xb, acc0b, 0, 0, 0);
      }
    }

    // Writer phase: bias + activation, stage gates to LDS.
#pragma unroll
    for (int r = 0; r < 4; ++r) {
      float v0 = acc0[r] + acc0b[r] + b0q[r];
      float v1 = acc1a[r] + acc1b[r] + b1q[r];
      float a0v = (p == 2) ? tanh_fast(v0) : sigm(v0);
      float a1v = (p == 2) ? tanh_fast(v1) : sigm(v1);
      sG0[wv][p * 64 + r * 16 + l15] = a0v;
      sG1[wv][p * 64 + r * 16 + l15] = a1v;
    }
    __syncthreads();

    // Reader phase: lane <-> (col j=p, batch l15). Update c, compute h -> sH bits.
    if (it < T_) {
      float gi = sG0[wv][0 * 64 + p * 16 + l15];
      float gf = sG0[wv][1 * 64 + p * 16 + l15];
      float gg = sG0[wv][2 * 64 + p * 16 + l15];
      float go = sG0[wv][3 * 64 + p * 16 + l15];
      c0 = gf * c0 + gi * gg;
      float h = go * tanh_fast(c0);
      union { __bf16 bf; unsigned short u; } cv; cv.bf = (__bf16)h;
      sH0[b][p] = cv.u;
    }
    if (it > 0) {
      float gi = sG1[wv][0 * 64 + p * 16 + l15];
      float gf = sG1[wv][1 * 64 + p * 16 + l15];
      float gg = sG1[wv][2 * 64 + p * 16 + l15];
      float go = sG1[wv][3 * 64 + p * 16 + l15];
      c1 = gf * c1 + gi * gg;
      float h = go * tanh_fast(c1);
      if (it < T_) {
        union { __bf16 bf; unsigned short u; } cv; cv.bf = (__bf16)h;
        sH1[b][p] = cv.u;
      } else {
        out[b * H_ + wg * 4 + p] = h;
      }
    }
    __syncthreads();

    // Packed publish: relaxed agent atomic dword stores (sc0 sc1 write-through).
    if (it < T_) {
      const int idx = tid & 127;
      const int bb = idx >> 1, pr = idx & 1;
      if (tid < 128) {
        unsigned v = (unsigned)sH0[bb][2 * pr] | ((unsigned)sH0[bb][2 * pr + 1] << 16);
        __hip_atomic_store(h0w + bb * (H_ / 2) + wg * 2 + pr, v,
                           __ATOMIC_RELAXED, __HIP_MEMORY_SCOPE_AGENT);
      } else if (it > 0) {
        unsigned v = (unsigned)sH1[bb][2 * pr] | ((unsigned)sH1[bb][2 * pr + 1] << 16);
        __hip_atomic_store(h1w + bb * (H_ / 2) + wg * 2 + pr, v,
                           __ATOMIC_RELAXED, __HIP_MEMORY_SCOPE_AGENT);
      }
    }

    // Flag barrier (no RMW, no wbl2).
    if (it != T_) {
      __syncthreads();  // drains vmcnt: this WG's publishes are at the coherence point
      const unsigned tgt = (unsigned)(it + 1);
      if (tid == 0)
        __hip_atomic_store(&flags[wg * 16], tgt, __ATOMIC_RELAXED, __HIP_MEMORY_SCOPE_AGENT);
      if (tid < 64) {  // wave 0: each lane polls 2 flag lines in parallel
        while (__hip_atomic_load(&flags[tid * 16], __ATOMIC_RELAXED,
                                 __HIP_MEMORY_SCOPE_AGENT) < tgt ||
               __hip_atomic_load(&flags[(tid + 64) * 16], __ATOMIC_RELAXED,
                                 __HIP_MEMORY_SCOPE_AGENT) < tgt)
          __builtin_amdgcn_s_sleep(1);
      }
      __syncthreads();  // all 128 WGs have arrived
      if (tid < 64)     // one acquire fence per WG: buffer_inv sc1 (drop stale L1/L2)
        __builtin_amdgcn_fence(__ATOMIC_ACQUIRE, "agent");
      __syncthreads();  // no wave issues loads before the inv
    }
  }
}

// Workspace layout:
//   [0]        flags: 128 x 64B = 8 KiB
//   [8192]     h0_pub: 4 gens x 64x512x2B = 262144 B
//   [270336]   h1_pub: 262144 B
//   [1 MiB]    xT: 16 MiB
// Zeroed region: [0, 532480).
extern "C" void kernel_launch(void* const* d_in, const int* in_sizes, int n_in,
                              void* d_out, int out_size, void* d_ws, size_t ws_size,
                              hipStream_t stream) {
  const float* x    = (const float*)d_in[0];
  const float* Wih0 = (const float*)d_in[1];
  const float* Whh0 = (const float*)d_in[2];
  const float* bih0 = (const float*)d_in[3];
  const float* bhh0 = (const float*)d_in[4];
  const float* Wih1 = (const float*)d_in[5];
  const float* Whh1 = (const float*)d_in[6];
  const float* bih1 = (const float*)d_in[7];
  const float* bhh1 = (const float*)d_in[8];
  float* out = (float*)d_out;

  char* ws = (char*)d_ws;
  unsigned* flags = (unsigned*)ws;
  __bf16* h0p = (__bf16*)(ws + 8192);
  __bf16* h1p = (__bf16*)(ws + 8192 + 4 * B_ * H_ * 2);
  __bf16* xT  = (__bf16*)(ws + (1 << 20));

  hipMemsetAsync(ws, 0, 8192 + 8 * B_ * H_ * 2, stream);

  transpose_x_kernel<<<dim3(B_ * 16), dim3(256), 0, stream>>>(x, xT);

  lstm_persistent<<<dim3(NWG), dim3(256), 0, stream>>>(
      xT, Wih0, Whh0, bih0, bhh0, Wih1, Whh1, bih1, bhh1,
      h0p, h1p, flags, out);
}